// Round 1
// baseline (854.968 us; speedup 1.0000x reference)
//
#include <hip/hip_runtime.h>
#include <stdint.h>

// SDFNetwork: instant-ngp hashgrid encode (L=16, F=2, T=2^19, base=16, scale=1.3819)
// + fully-fused MLP 32 -> 64 -> 64 -> 1 (bias-free, ReLU hidden, linear out), all fp32.
// One fused kernel, 1 point per thread, weights staged in LDS.

#define NLVL 16
#define TBLSZ (1u << 19)
#define HID 64
#define ENCD 32

// res_l = floor(16 * 1.3819^l); levels 0..4 are dense ((res+1)^3 <= T), 5..15 hashed.
__device__ constexpr int RES[NLVL] = {16, 22, 30, 42, 58, 80, 111, 153, 212, 294,
                                      406, 561, 775, 1072, 1481, 2047};

__global__ __launch_bounds__(256)
void sdf_fused(const float* __restrict__ x,
               const float* __restrict__ tables,
               const float* __restrict__ W0,
               const float* __restrict__ W1,
               const float* __restrict__ W2,
               float* __restrict__ out, int npts)
{
    __shared__ float sW0[ENCD * HID];   // [i][j], j contiguous (as given)
    __shared__ float sW1t[HID * HID];   // transposed: [j][i], i contiguous
    __shared__ float sW2[HID];

    const int tid = threadIdx.x;
    for (int idx = tid; idx < ENCD * HID; idx += 256) sW0[idx] = W0[idx];
    for (int idx = tid; idx < HID * HID; idx += 256) {
        const int j = idx >> 6, i = idx & 63;
        sW1t[idx] = W1[(i << 6) + j];
    }
    if (tid < HID) sW2[tid] = W2[tid];
    __syncthreads();

    const int n = blockIdx.x * 256 + tid;
    if (n >= npts) return;

    const float xr = x[3 * n + 0];
    const float yr = x[3 * n + 1];
    const float zr = x[3 * n + 2];
    const float x01 = (xr + 1.0f) * 0.5f;
    const float y01 = (yr + 1.0f) * 0.5f;
    const float z01 = (zr + 1.0f) * 0.5f;

    float enc[ENCD];

    #pragma unroll
    for (int l = 0; l < NLVL; ++l) {
        const int res = RES[l];
        const float fres = (float)res;
        const float px = x01 * fres, py = y01 * fres, pz = z01 * fres;
        const float fx = floorf(px), fy = floorf(py), fz = floorf(pz);
        const float tx = px - fx, ty = py - fy, tz = pz - fz;
        const uint32_t cx = (uint32_t)fx, cy = (uint32_t)fy, cz = (uint32_t)fz;

        uint32_t i000, i001, i010, i011, i100, i101, i110, i111;
        if (l < 5) {
            // dense: idx = cx + cy*(res+1) + cz*(res+1)^2  (uint32)
            const uint32_t s1 = (uint32_t)(res + 1);
            const uint32_t s2 = s1 * s1;
            const uint32_t bx0 = cx, bx1 = cx + 1u;
            const uint32_t by0 = cy * s1, by1 = by0 + s1;
            const uint32_t bz0 = cz * s2, bz1 = bz0 + s2;
            i000 = bx0 + by0 + bz0; i001 = bx0 + by0 + bz1;
            i010 = bx0 + by1 + bz0; i011 = bx0 + by1 + bz1;
            i100 = bx1 + by0 + bz0; i101 = bx1 + by0 + bz1;
            i110 = bx1 + by1 + bz0; i111 = bx1 + by1 + bz1;
        } else {
            // instant-ngp spatial hash: (cx*1) ^ (cy*2654435761) ^ (cz*805459861), uint32 wrap
            const uint32_t P1 = 2654435761u, P2 = 805459861u;
            const uint32_t M = TBLSZ - 1u;
            const uint32_t hx0 = cx, hx1 = cx + 1u;
            const uint32_t hy0 = cy * P1, hy1 = hy0 + P1;
            const uint32_t hz0 = cz * P2, hz1 = hz0 + P2;
            i000 = (hx0 ^ hy0 ^ hz0) & M; i001 = (hx0 ^ hy0 ^ hz1) & M;
            i010 = (hx0 ^ hy1 ^ hz0) & M; i011 = (hx0 ^ hy1 ^ hz1) & M;
            i100 = (hx1 ^ hy0 ^ hz0) & M; i101 = (hx1 ^ hy0 ^ hz1) & M;
            i110 = (hx1 ^ hy1 ^ hz0) & M; i111 = (hx1 ^ hy1 ^ hz1) & M;
        }

        const float2* tab = (const float2*)tables + (size_t)l * TBLSZ;
        const float2 f000 = tab[i000], f001 = tab[i001];
        const float2 f010 = tab[i010], f011 = tab[i011];
        const float2 f100 = tab[i100], f101 = tab[i101];
        const float2 f110 = tab[i110], f111 = tab[i111];

        const float wx1 = tx, wx0 = 1.0f - tx;
        const float wy1 = ty, wy0 = 1.0f - ty;
        const float wz1 = tz, wz0 = 1.0f - tz;
        const float w00 = wx0 * wy0, w01 = wx0 * wy1;
        const float w10 = wx1 * wy0, w11 = wx1 * wy1;
        const float w000 = w00 * wz0, w001 = w00 * wz1;
        const float w010 = w01 * wz0, w011 = w01 * wz1;
        const float w100 = w10 * wz0, w101 = w10 * wz1;
        const float w110 = w11 * wz0, w111 = w11 * wz1;

        float e0 = w000 * f000.x;
        float e1 = w000 * f000.y;
        e0 = fmaf(w001, f001.x, e0); e1 = fmaf(w001, f001.y, e1);
        e0 = fmaf(w010, f010.x, e0); e1 = fmaf(w010, f010.y, e1);
        e0 = fmaf(w011, f011.x, e0); e1 = fmaf(w011, f011.y, e1);
        e0 = fmaf(w100, f100.x, e0); e1 = fmaf(w100, f100.y, e1);
        e0 = fmaf(w101, f101.x, e0); e1 = fmaf(w101, f101.y, e1);
        e0 = fmaf(w110, f110.x, e0); e1 = fmaf(w110, f110.y, e1);
        e0 = fmaf(w111, f111.x, e0); e1 = fmaf(w111, f111.y, e1);

        enc[2 * l + 0] = e0;
        enc[2 * l + 1] = e1;
    }

    // Layer 1: h1 = relu(enc @ W0), j-inner (64 independent accumulators, uniform
    // LDS reads of contiguous W0 rows -> ds_read_b128 broadcast).
    float h1[HID];
    #pragma unroll
    for (int j = 0; j < HID; ++j) h1[j] = 0.0f;
    #pragma unroll
    for (int i = 0; i < ENCD; ++i) {
        const float e = enc[i];
        const float* wr = &sW0[i << 6];
        #pragma unroll
        for (int j = 0; j < HID; ++j) h1[j] = fmaf(e, wr[j], h1[j]);
    }
    #pragma unroll
    for (int j = 0; j < HID; ++j) h1[j] = fmaxf(h1[j], 0.0f);

    // Layers 2+3 fused: acc = sum_j relu(h1 . W1t[j]) * W2[j]; 4-way split
    // accumulators break the fma dependency chain.
    float acc = 0.0f;
    #pragma unroll
    for (int j = 0; j < HID; ++j) {
        const float* wr = &sW1t[j << 6];
        float t0 = 0.0f, t1 = 0.0f, t2 = 0.0f, t3 = 0.0f;
        #pragma unroll
        for (int i = 0; i < HID; i += 4) {
            t0 = fmaf(h1[i + 0], wr[i + 0], t0);
            t1 = fmaf(h1[i + 1], wr[i + 1], t1);
            t2 = fmaf(h1[i + 2], wr[i + 2], t2);
            t3 = fmaf(h1[i + 3], wr[i + 3], t3);
        }
        const float t = (t0 + t1) + (t2 + t3);
        acc = fmaf(fmaxf(t, 0.0f), sW2[j], acc);
    }

    out[n] = acc;
}

extern "C" void kernel_launch(void* const* d_in, const int* in_sizes, int n_in,
                              void* d_out, int out_size, void* d_ws, size_t ws_size,
                              hipStream_t stream) {
    const float* x      = (const float*)d_in[0];
    const float* tables = (const float*)d_in[1];
    const float* W0     = (const float*)d_in[2];
    const float* W1     = (const float*)d_in[3];
    const float* W2     = (const float*)d_in[4];
    float* out = (float*)d_out;

    const int npts = in_sizes[0] / 3;
    const int grid = (npts + 255) / 256;
    sdf_fused<<<grid, 256, 0, stream>>>(x, tables, W0, W1, W2, out, npts);
}